// Round 1
// baseline (2691.215 us; speedup 1.0000x reference)
//
#include <hip/hip_runtime.h>

#define BATCH 16

__device__ __forceinline__ float fast_tanh(float v) {
    // tanh(x) = sign(x) * (1 - 2/(exp(2|x|)+1)); exp overflow -> inf -> t=1, correct.
    float a = fabsf(v);
    float e = __expf(2.0f * a);
    float t = 1.0f - 2.0f / (e + 1.0f);
    return copysignf(t, v);
}

__device__ __forceinline__ float blend(float lin, float alpha) {
    // (1-a)*lin + a*tanh(lin) == lin + a*(tanh(lin)-lin)
    return lin + alpha * (fast_tanh(lin) - lin);
}

// ---------------- fast path: (N,B)-transposed x and y in workspace ----------------

// xT[n*B+b] = x[b*N+n]; yT[n*B+b] = 0
__global__ __launch_bounds__(256) void k_transpose(const float* __restrict__ x,
                                                   float* __restrict__ xT,
                                                   float* __restrict__ yT, int N) {
    int n = blockIdx.x * blockDim.x + threadIdx.x;
    if (n >= N) return;
    float v[BATCH];
#pragma unroll
    for (int b = 0; b < BATCH; ++b) v[b] = x[(size_t)b * N + n];  // coalesced per b
    float4* dst = (float4*)(xT + (size_t)n * BATCH);
    float4* zr  = (float4*)(yT + (size_t)n * BATCH);
#pragma unroll
    for (int i = 0; i < BATCH / 4; ++i) {
        dst[i] = make_float4(v[4 * i], v[4 * i + 1], v[4 * i + 2], v[4 * i + 3]);
        zr[i]  = make_float4(0.f, 0.f, 0.f, 0.f);
    }
}

// one thread per edge: gather 64B from xT, edge nonlin, 16 contiguous atomics into yT
__global__ __launch_bounds__(256) void k_edge(const int* __restrict__ src,
                                              const int* __restrict__ dst,
                                              const float* __restrict__ ea,
                                              const float* __restrict__ ew,
                                              const float* __restrict__ eb,
                                              const float* __restrict__ xT,
                                              float* __restrict__ yT, int E) {
    int e = blockIdx.x * blockDim.x + threadIdx.x;
    if (e >= E) return;
    int s = src[e], d = dst[e];
    float a = ea[e], w = ew[e], bb = eb[e];
    const float4* xs = (const float4*)(xT + (size_t)s * BATCH);
    float* yd = yT + (size_t)d * BATCH;
#pragma unroll
    for (int i = 0; i < BATCH / 4; ++i) {
        float4 xv = xs[i];
        float m0 = blend(w * xv.x + bb, a);
        float m1 = blend(w * xv.y + bb, a);
        float m2 = blend(w * xv.z + bb, a);
        float m3 = blend(w * xv.w + bb, a);
        unsafeAtomicAdd(yd + 4 * i + 0, m0);
        unsafeAtomicAdd(yd + 4 * i + 1, m1);
        unsafeAtomicAdd(yd + 4 * i + 2, m2);
        unsafeAtomicAdd(yd + 4 * i + 3, m3);
    }
}

// thread per node: read yT[n*16..], node nonlin, write out[b*N+n] (coalesced per b)
__global__ __launch_bounds__(256) void k_node(const float* __restrict__ yT,
                                              const float* __restrict__ na,
                                              const float* __restrict__ nw,
                                              const float* __restrict__ nb,
                                              float* __restrict__ out, int N) {
    int n = blockIdx.x * blockDim.x + threadIdx.x;
    if (n >= N) return;
    float a = na[n], w = nw[n], bb = nb[n];
    const float4* ys = (const float4*)(yT + (size_t)n * BATCH);
#pragma unroll
    for (int i = 0; i < BATCH / 4; ++i) {
        float4 y = ys[i];
        out[(size_t)(4 * i + 0) * N + n] = blend(w * y.x + bb, a);
        out[(size_t)(4 * i + 1) * N + n] = blend(w * y.y + bb, a);
        out[(size_t)(4 * i + 2) * N + n] = blend(w * y.z + bb, a);
        out[(size_t)(4 * i + 3) * N + n] = blend(w * y.w + bb, a);
    }
}

// ---------------- fallback path: accumulate directly in d_out (B,N) ----------------

__global__ __launch_bounds__(256) void k_edge_direct(const int* __restrict__ src,
                                                     const int* __restrict__ dst,
                                                     const float* __restrict__ ea,
                                                     const float* __restrict__ ew,
                                                     const float* __restrict__ eb,
                                                     const float* __restrict__ x,
                                                     float* __restrict__ out, int N, int E) {
    int e = blockIdx.x * blockDim.x + threadIdx.x;
    if (e >= E) return;
    int s = src[e], d = dst[e];
    float a = ea[e], w = ew[e], bb = eb[e];
#pragma unroll
    for (int b = 0; b < BATCH; ++b) {
        float xv = x[(size_t)b * N + s];
        unsafeAtomicAdd(out + (size_t)b * N + d, blend(w * xv + bb, a));
    }
}

__global__ __launch_bounds__(256) void k_node_inplace(const float* __restrict__ na,
                                                      const float* __restrict__ nw,
                                                      const float* __restrict__ nb,
                                                      float* __restrict__ out, int N) {
    int n = blockIdx.x * blockDim.x + threadIdx.x;
    if (n >= N) return;
    float a = na[n], w = nw[n], bb = nb[n];
#pragma unroll
    for (int b = 0; b < BATCH; ++b) {
        size_t idx = (size_t)b * N + n;
        out[idx] = blend(w * out[idx] + bb, a);
    }
}

extern "C" void kernel_launch(void* const* d_in, const int* in_sizes, int n_in,
                              void* d_out, int out_size, void* d_ws, size_t ws_size,
                              hipStream_t stream) {
    const float* x   = (const float*)d_in[0];
    const int*   src = (const int*)  d_in[1];
    const int*   dst = (const int*)  d_in[2];
    const float* ea  = (const float*)d_in[3];
    const float* ew  = (const float*)d_in[4];
    const float* eb  = (const float*)d_in[5];
    const float* na  = (const float*)d_in[6];
    const float* nw  = (const float*)d_in[7];
    const float* nb  = (const float*)d_in[8];
    float* out = (float*)d_out;

    const int E = in_sizes[1];
    const int N = in_sizes[6];
    const int bt = 256;

    size_t need = 2ull * (size_t)N * BATCH * sizeof(float);
    if (ws_size >= need) {
        float* xT = (float*)d_ws;
        float* yT = xT + (size_t)N * BATCH;
        k_transpose<<<(N + bt - 1) / bt, bt, 0, stream>>>(x, xT, yT, N);
        k_edge<<<(E + bt - 1) / bt, bt, 0, stream>>>(src, dst, ea, ew, eb, xT, yT, E);
        k_node<<<(N + bt - 1) / bt, bt, 0, stream>>>(yT, na, nw, nb, out, N);
    } else {
        hipMemsetAsync(d_out, 0, (size_t)out_size * sizeof(float), stream);
        k_edge_direct<<<(E + bt - 1) / bt, bt, 0, stream>>>(src, dst, ea, ew, eb, x, out, N, E);
        k_node_inplace<<<(N + bt - 1) / bt, bt, 0, stream>>>(na, nw, nb, out, N);
    }
}

// Round 3
// 494.651 us; speedup vs baseline: 5.4406x; 5.4406x over previous
//
#include <hip/hip_runtime.h>

#define BATCH 16
#define TILE 2048  // scan tile: 256 threads x 8 values

__device__ __forceinline__ float fast_tanh(float v) {
    float a = fabsf(v);
    float e = __expf(2.0f * a);
    float t = 1.0f - 2.0f / (e + 1.0f);
    return copysignf(t, v);
}

__device__ __forceinline__ float blend(float lin, float alpha) {
    return lin + alpha * (fast_tanh(lin) - lin);
}

// ---------------- CSR counting-sort fast path ----------------

// xT[n*B+b] = x[b*N+n]
__global__ __launch_bounds__(256) void k_transpose(const float* __restrict__ x,
                                                   float* __restrict__ xT, int N) {
    int n = blockIdx.x * blockDim.x + threadIdx.x;
    if (n >= N) return;
    float v[BATCH];
#pragma unroll
    for (int b = 0; b < BATCH; ++b) v[b] = x[(size_t)b * N + n];
    float4* dst = (float4*)(xT + (size_t)n * BATCH);
#pragma unroll
    for (int i = 0; i < BATCH / 4; ++i)
        dst[i] = make_float4(v[4 * i], v[4 * i + 1], v[4 * i + 2], v[4 * i + 3]);
}

// 4 edges per thread via int4 loads; same atomic count, 4x fewer waves
__global__ __launch_bounds__(256) void k_hist(const int* __restrict__ dst,
                                              int* __restrict__ counts, int E) {
    int i = blockIdx.x * blockDim.x + threadIdx.x;
    int base = i * 4;
    if (base + 3 < E) {
        int4 d = *(const int4*)(dst + base);
        atomicAdd(&counts[d.x], 1);
        atomicAdd(&counts[d.y], 1);
        atomicAdd(&counts[d.z], 1);
        atomicAdd(&counts[d.w], 1);
    } else {
        for (int e = base; e < E; ++e) atomicAdd(&counts[dst[e]], 1);
    }
}

// per-tile exclusive scan; tile totals to tileSums
__global__ __launch_bounds__(256) void k_scan_tiles(const int* __restrict__ counts,
                                                    int* __restrict__ offsets,
                                                    int* __restrict__ tileSums, int N) {
    __shared__ int sdata[256];
    int t = threadIdx.x;
    int base = blockIdx.x * TILE + t * 8;
    int v[8];
    int s = 0;
#pragma unroll
    for (int i = 0; i < 8; ++i) {
        v[i] = (base + i < N) ? counts[base + i] : 0;
        s += v[i];
    }
    sdata[t] = s;
    __syncthreads();
    for (int off = 1; off < 256; off <<= 1) {
        int add = 0;
        if (t >= off) add = sdata[t - off];
        __syncthreads();
        sdata[t] += add;
        __syncthreads();
    }
    int run = sdata[t] - s;  // exclusive prefix of this thread's chunk within tile
#pragma unroll
    for (int i = 0; i < 8; ++i) {
        if (base + i < N) offsets[base + i] = run;
        run += v[i];
    }
    if (t == 255) tileSums[blockIdx.x] = sdata[255];
}

// single-block exclusive scan of tile sums (nTiles <= 256)
__global__ __launch_bounds__(256) void k_scan_sums(int* __restrict__ tileSums,
                                                   int* __restrict__ offsets,
                                                   int nTiles, int N, int E) {
    __shared__ int sh[256];
    int t = threadIdx.x;
    int v = (t < nTiles) ? tileSums[t] : 0;
    sh[t] = v;
    __syncthreads();
    for (int off = 1; off < 256; off <<= 1) {
        int add = 0;
        if (t >= off) add = sh[t - off];
        __syncthreads();
        sh[t] += add;
        __syncthreads();
    }
    if (t < nTiles) tileSums[t] = sh[t] - v;  // exclusive
    if (t == 0) offsets[N] = E;
}

__global__ __launch_bounds__(256) void k_add_cursor(int* __restrict__ offsets,
                                                    const int* __restrict__ tileSums,
                                                    int* __restrict__ cursor, int N) {
    int i = blockIdx.x * blockDim.x + threadIdx.x;
    if (i >= N) return;
    int o = offsets[i] + tileSums[i / TILE];
    offsets[i] = o;
    cursor[i] = o;
}

// payload = {src (bitcast), edge_alpha, edge_w, edge_b}
__global__ __launch_bounds__(256) void k_scatter(const int* __restrict__ src,
                                                 const int* __restrict__ dst,
                                                 const float* __restrict__ ea,
                                                 const float* __restrict__ ew,
                                                 const float* __restrict__ eb,
                                                 int* __restrict__ cursor,
                                                 float4* __restrict__ sorted, int E) {
    int e = blockIdx.x * blockDim.x + threadIdx.x;
    if (e >= E) return;
    int d = dst[e];
    int p = atomicAdd(&cursor[d], 1);
    sorted[p] = make_float4(__int_as_float(src[e]), ea[e], ew[e], eb[e]);
}

// one thread per node: sum incoming edges, node nonlin, write out. No atomics.
__global__ __launch_bounds__(256) void k_gather(const float4* __restrict__ sorted,
                                                const int* __restrict__ offsets,
                                                const float* __restrict__ xT,
                                                const float* __restrict__ na,
                                                const float* __restrict__ nw,
                                                const float* __restrict__ nb,
                                                float* __restrict__ out, int N) {
    int n = blockIdx.x * blockDim.x + threadIdx.x;
    if (n >= N) return;
    int beg = offsets[n], end = offsets[n + 1];
    float acc[BATCH];
#pragma unroll
    for (int b = 0; b < BATCH; ++b) acc[b] = 0.f;
    for (int r = beg; r < end; ++r) {
        float4 pl = sorted[r];
        int s = __float_as_int(pl.x);
        float a = pl.y, w = pl.z, bb = pl.w;
        const float4* xs = (const float4*)(xT + (size_t)s * BATCH);
#pragma unroll
        for (int i = 0; i < BATCH / 4; ++i) {
            float4 xv = xs[i];
            acc[4 * i + 0] += blend(w * xv.x + bb, a);
            acc[4 * i + 1] += blend(w * xv.y + bb, a);
            acc[4 * i + 2] += blend(w * xv.z + bb, a);
            acc[4 * i + 3] += blend(w * xv.w + bb, a);
        }
    }
    float a = na[n], w = nw[n], bb = nb[n];
#pragma unroll
    for (int b = 0; b < BATCH; ++b)
        out[(size_t)b * N + n] = blend(w * acc[b] + bb, a);
}

// ---------------- fallback: direct atomic path ----------------

__global__ __launch_bounds__(256) void k_edge_direct(const int* __restrict__ src,
                                                     const int* __restrict__ dst,
                                                     const float* __restrict__ ea,
                                                     const float* __restrict__ ew,
                                                     const float* __restrict__ eb,
                                                     const float* __restrict__ x,
                                                     float* __restrict__ out, int N, int E) {
    int e = blockIdx.x * blockDim.x + threadIdx.x;
    if (e >= E) return;
    int s = src[e], d = dst[e];
    float a = ea[e], w = ew[e], bb = eb[e];
#pragma unroll
    for (int b = 0; b < BATCH; ++b) {
        float xv = x[(size_t)b * N + s];
        unsafeAtomicAdd(out + (size_t)b * N + d, blend(w * xv + bb, a));
    }
}

__global__ __launch_bounds__(256) void k_node_inplace(const float* __restrict__ na,
                                                      const float* __restrict__ nw,
                                                      const float* __restrict__ nb,
                                                      float* __restrict__ out, int N) {
    int n = blockIdx.x * blockDim.x + threadIdx.x;
    if (n >= N) return;
    float a = na[n], w = nw[n], bb = nb[n];
#pragma unroll
    for (int b = 0; b < BATCH; ++b) {
        size_t idx = (size_t)b * N + n;
        out[idx] = blend(w * out[idx] + bb, a);
    }
}

extern "C" void kernel_launch(void* const* d_in, const int* in_sizes, int n_in,
                              void* d_out, int out_size, void* d_ws, size_t ws_size,
                              hipStream_t stream) {
    const float* x   = (const float*)d_in[0];
    const int*   src = (const int*)  d_in[1];
    const int*   dst = (const int*)  d_in[2];
    const float* ea  = (const float*)d_in[3];
    const float* ew  = (const float*)d_in[4];
    const float* eb  = (const float*)d_in[5];
    const float* na  = (const float*)d_in[6];
    const float* nw  = (const float*)d_in[7];
    const float* nb  = (const float*)d_in[8];
    float* out = (float*)d_out;

    const int E = in_sizes[1];
    const int N = in_sizes[6];
    const int bt = 256;
    const int nTiles = (N + TILE - 1) / TILE;

    // workspace layout
    float*  xT      = (float*)d_ws;                          // N*16 floats
    float4* sorted  = (float4*)(xT + (size_t)N * BATCH);     // E float4 (16B-aligned)
    int*    counts  = (int*)(sorted + (size_t)E);            // N
    int*    offsets = counts + N;                            // N+1
    int*    cursor  = offsets + (N + 1);                     // N
    int*    tileSums = cursor + N;                           // nTiles (<=256)

    size_t need = (size_t)N * BATCH * sizeof(float) + (size_t)E * sizeof(float4) +
                  ((size_t)3 * N + 1 + 256) * sizeof(int);

    if (ws_size >= need && nTiles <= 256) {
        hipMemsetAsync(counts, 0, (size_t)N * sizeof(int), stream);
        k_transpose<<<(N + bt - 1) / bt, bt, 0, stream>>>(x, xT, N);
        k_hist<<<(E / 4 + bt - 1) / bt + 1, bt, 0, stream>>>(dst, counts, E);
        k_scan_tiles<<<nTiles, 256, 0, stream>>>(counts, offsets, tileSums, N);
        k_scan_sums<<<1, 256, 0, stream>>>(tileSums, offsets, nTiles, N, E);
        k_add_cursor<<<(N + bt - 1) / bt, bt, 0, stream>>>(offsets, tileSums, cursor, N);
        k_scatter<<<(E + bt - 1) / bt, bt, 0, stream>>>(src, dst, ea, ew, eb, cursor, sorted, E);
        k_gather<<<(N + bt - 1) / bt, bt, 0, stream>>>(sorted, offsets, xT, na, nw, nb, out, N);
    } else {
        hipMemsetAsync(d_out, 0, (size_t)out_size * sizeof(float), stream);
        k_edge_direct<<<(E + bt - 1) / bt, bt, 0, stream>>>(src, dst, ea, ew, eb, x, out, N, E);
        k_node_inplace<<<(N + bt - 1) / bt, bt, 0, stream>>>(na, nw, nb, out, N);
    }
}

// Round 5
// 400.927 us; speedup vs baseline: 6.7125x; 1.2338x over previous
//
#include <hip/hip_runtime.h>

#define BATCH 16
#define TILE 2048  // scan tile: 256 threads x 8 values

__device__ __forceinline__ float fast_tanh(float v) {
    float a = fabsf(v);
    float e = __expf(2.0f * a);
    float t = 1.0f - 2.0f / (e + 1.0f);
    return copysignf(t, v);
}

__device__ __forceinline__ float blend(float lin, float alpha) {
    return lin + alpha * (fast_tanh(lin) - lin);
}

// ---------------- CSR counting-sort fast path ----------------

// xT[n*B+b] = x[b*N+n]
__global__ __launch_bounds__(256) void k_transpose(const float* __restrict__ x,
                                                   float* __restrict__ xT, int N) {
    int n = blockIdx.x * blockDim.x + threadIdx.x;
    if (n >= N) return;
    float v[BATCH];
#pragma unroll
    for (int b = 0; b < BATCH; ++b) v[b] = x[(size_t)b * N + n];
    float4* dst = (float4*)(xT + (size_t)n * BATCH);
#pragma unroll
    for (int i = 0; i < BATCH / 4; ++i)
        dst[i] = make_float4(v[4 * i], v[4 * i + 1], v[4 * i + 2], v[4 * i + 3]);
}

// counts + per-edge rank in ONE atomic pass (the atomic return IS the rank)
__global__ __launch_bounds__(256) void k_hist_rank(const int* __restrict__ dst,
                                                   int* __restrict__ counts,
                                                   int* __restrict__ rank, int E) {
    int i = blockIdx.x * blockDim.x + threadIdx.x;
    int base = i * 4;
    if (base + 3 < E) {
        int4 d = *(const int4*)(dst + base);
        int r0 = atomicAdd(&counts[d.x], 1);
        int r1 = atomicAdd(&counts[d.y], 1);
        int r2 = atomicAdd(&counts[d.z], 1);
        int r3 = atomicAdd(&counts[d.w], 1);
        *(int4*)(rank + base) = make_int4(r0, r1, r2, r3);
    } else {
        for (int e = base; e < E; ++e) rank[e] = atomicAdd(&counts[dst[e]], 1);
    }
}

// plain histogram (cursor fallback path)
__global__ __launch_bounds__(256) void k_hist(const int* __restrict__ dst,
                                              int* __restrict__ counts, int E) {
    int i = blockIdx.x * blockDim.x + threadIdx.x;
    int base = i * 4;
    if (base + 3 < E) {
        int4 d = *(const int4*)(dst + base);
        atomicAdd(&counts[d.x], 1);
        atomicAdd(&counts[d.y], 1);
        atomicAdd(&counts[d.z], 1);
        atomicAdd(&counts[d.w], 1);
    } else {
        for (int e = base; e < E; ++e) atomicAdd(&counts[dst[e]], 1);
    }
}

// per-tile exclusive scan; tile totals to tileSums
__global__ __launch_bounds__(256) void k_scan_tiles(const int* __restrict__ counts,
                                                    int* __restrict__ offsets,
                                                    int* __restrict__ tileSums, int N) {
    __shared__ int sdata[256];
    int t = threadIdx.x;
    int base = blockIdx.x * TILE + t * 8;
    int v[8];
    int s = 0;
#pragma unroll
    for (int i = 0; i < 8; ++i) {
        v[i] = (base + i < N) ? counts[base + i] : 0;
        s += v[i];
    }
    sdata[t] = s;
    __syncthreads();
    for (int off = 1; off < 256; off <<= 1) {
        int add = 0;
        if (t >= off) add = sdata[t - off];
        __syncthreads();
        sdata[t] += add;
        __syncthreads();
    }
    int run = sdata[t] - s;
#pragma unroll
    for (int i = 0; i < 8; ++i) {
        if (base + i < N) offsets[base + i] = run;
        run += v[i];
    }
    if (t == 255) tileSums[blockIdx.x] = sdata[255];
}

// single-block exclusive scan of tile sums (nTiles <= 256)
__global__ __launch_bounds__(256) void k_scan_sums(int* __restrict__ tileSums,
                                                   int* __restrict__ offsets,
                                                   int nTiles, int N, int E) {
    __shared__ int sh[256];
    int t = threadIdx.x;
    int v = (t < nTiles) ? tileSums[t] : 0;
    sh[t] = v;
    __syncthreads();
    for (int off = 1; off < 256; off <<= 1) {
        int add = 0;
        if (t >= off) add = sh[t - off];
        __syncthreads();
        sh[t] += add;
        __syncthreads();
    }
    if (t < nTiles) tileSums[t] = sh[t] - v;  // exclusive
    if (t == 0) offsets[N] = E;
}

// offsets += tile base (rank path: no cursor needed)
__global__ __launch_bounds__(256) void k_add(int* __restrict__ offsets,
                                             const int* __restrict__ tileSums, int N) {
    int i = blockIdx.x * blockDim.x + threadIdx.x;
    if (i >= N) return;
    offsets[i] += tileSums[i / TILE];
}

__global__ __launch_bounds__(256) void k_add_cursor(int* __restrict__ offsets,
                                                    const int* __restrict__ tileSums,
                                                    int* __restrict__ cursor, int N) {
    int i = blockIdx.x * blockDim.x + threadIdx.x;
    if (i >= N) return;
    int o = offsets[i] + tileSums[i / TILE];
    offsets[i] = o;
    cursor[i] = o;
}

// atomic-free scatter: slot = offsets[dst] + rank; 4 edges/thread, vectorized
__global__ __launch_bounds__(256) void k_scatter_rank(const int* __restrict__ src,
                                                      const int* __restrict__ dst,
                                                      const float* __restrict__ ea,
                                                      const float* __restrict__ ew,
                                                      const float* __restrict__ eb,
                                                      const int* __restrict__ rank,
                                                      const int* __restrict__ offsets,
                                                      float4* __restrict__ sorted, int E) {
    int i = blockIdx.x * blockDim.x + threadIdx.x;
    int base = i * 4;
    if (base + 3 < E) {
        int4 s = *(const int4*)(src + base);
        int4 d = *(const int4*)(dst + base);
        int4 r = *(const int4*)(rank + base);
        float4 a = *(const float4*)(ea + base);
        float4 w = *(const float4*)(ew + base);
        float4 b = *(const float4*)(eb + base);
        sorted[offsets[d.x] + r.x] = make_float4(__int_as_float(s.x), a.x, w.x, b.x);
        sorted[offsets[d.y] + r.y] = make_float4(__int_as_float(s.y), a.y, w.y, b.y);
        sorted[offsets[d.z] + r.z] = make_float4(__int_as_float(s.z), a.z, w.z, b.z);
        sorted[offsets[d.w] + r.w] = make_float4(__int_as_float(s.w), a.w, w.w, b.w);
    } else {
        for (int e = base; e < E; ++e)
            sorted[offsets[dst[e]] + rank[e]] =
                make_float4(__int_as_float(src[e]), ea[e], ew[e], eb[e]);
    }
}

// cursor-based scatter (fallback path, smaller ws)
__global__ __launch_bounds__(256) void k_scatter(const int* __restrict__ src,
                                                 const int* __restrict__ dst,
                                                 const float* __restrict__ ea,
                                                 const float* __restrict__ ew,
                                                 const float* __restrict__ eb,
                                                 int* __restrict__ cursor,
                                                 float4* __restrict__ sorted, int E) {
    int e = blockIdx.x * blockDim.x + threadIdx.x;
    if (e >= E) return;
    int d = dst[e];
    int p = atomicAdd(&cursor[d], 1);
    sorted[p] = make_float4(__int_as_float(src[e]), ea[e], ew[e], eb[e]);
}

// 4 lanes per node: lane j owns batch-quadrant j (float4). No atomics, no reduce.
__global__ __launch_bounds__(256) void k_gather(const float4* __restrict__ sorted,
                                                const int* __restrict__ offsets,
                                                const float* __restrict__ xT,
                                                const float* __restrict__ na,
                                                const float* __restrict__ nw,
                                                const float* __restrict__ nb,
                                                float* __restrict__ out, int N) {
    int t = blockIdx.x * blockDim.x + threadIdx.x;
    int n = t >> 2;
    int j = t & 3;
    if (n >= N) return;
    int beg = offsets[n], end = offsets[n + 1];
    float4 acc = make_float4(0.f, 0.f, 0.f, 0.f);
    for (int r = beg; r < end; ++r) {
        float4 pl = sorted[r];  // {src, alpha, w, b} — same addr for the 4 lanes
        int s = __float_as_int(pl.x);
        float4 xv = *(const float4*)(xT + (size_t)s * BATCH + j * 4);
        acc.x += blend(pl.z * xv.x + pl.w, pl.y);
        acc.y += blend(pl.z * xv.y + pl.w, pl.y);
        acc.z += blend(pl.z * xv.z + pl.w, pl.y);
        acc.w += blend(pl.z * xv.w + pl.w, pl.y);
    }
    float a = na[n], w = nw[n], bb = nb[n];
    out[(size_t)(4 * j + 0) * N + n] = blend(w * acc.x + bb, a);
    out[(size_t)(4 * j + 1) * N + n] = blend(w * acc.y + bb, a);
    out[(size_t)(4 * j + 2) * N + n] = blend(w * acc.z + bb, a);
    out[(size_t)(4 * j + 3) * N + n] = blend(w * acc.w + bb, a);
}

// ---------------- fallback: direct atomic path ----------------

__global__ __launch_bounds__(256) void k_edge_direct(const int* __restrict__ src,
                                                     const int* __restrict__ dst,
                                                     const float* __restrict__ ea,
                                                     const float* __restrict__ ew,
                                                     const float* __restrict__ eb,
                                                     const float* __restrict__ x,
                                                     float* __restrict__ out, int N, int E) {
    int e = blockIdx.x * blockDim.x + threadIdx.x;
    if (e >= E) return;
    int s = src[e], d = dst[e];
    float a = ea[e], w = ew[e], bb = eb[e];
#pragma unroll
    for (int b = 0; b < BATCH; ++b) {
        float xv = x[(size_t)b * N + s];
        unsafeAtomicAdd(out + (size_t)b * N + d, blend(w * xv + bb, a));
    }
}

__global__ __launch_bounds__(256) void k_node_inplace(const float* __restrict__ na,
                                                      const float* __restrict__ nw,
                                                      const float* __restrict__ nb,
                                                      float* __restrict__ out, int N) {
    int n = blockIdx.x * blockDim.x + threadIdx.x;
    if (n >= N) return;
    float a = na[n], w = nw[n], bb = nb[n];
#pragma unroll
    for (int b = 0; b < BATCH; ++b) {
        size_t idx = (size_t)b * N + n;
        out[idx] = blend(w * out[idx] + bb, a);
    }
}

extern "C" void kernel_launch(void* const* d_in, const int* in_sizes, int n_in,
                              void* d_out, int out_size, void* d_ws, size_t ws_size,
                              hipStream_t stream) {
    const float* x   = (const float*)d_in[0];
    const int*   src = (const int*)  d_in[1];
    const int*   dst = (const int*)  d_in[2];
    const float* ea  = (const float*)d_in[3];
    const float* ew  = (const float*)d_in[4];
    const float* eb  = (const float*)d_in[5];
    const float* na  = (const float*)d_in[6];
    const float* nw  = (const float*)d_in[7];
    const float* nb  = (const float*)d_in[8];
    float* out = (float*)d_out;

    const int E = in_sizes[1];
    const int N = in_sizes[6];
    const int bt = 256;
    const int nTiles = (N + TILE - 1) / TILE;
    const int gE4 = ((E + 3) / 4 + bt - 1) / bt;  // grids for 4-edges/thread kernels

    // workspace layout (16B-aligned segments first)
    float*  xT      = (float*)d_ws;                          // N*16 floats (16B-mult)
    float4* sorted  = (float4*)(xT + (size_t)N * BATCH);     // E float4
    int*    rank    = (int*)(sorted + (size_t)E);            // E ints (16B-aligned)
    int*    counts  = rank + E;                              // N
    int*    offsets = counts + N;                            // N+1
    int*    tileSums = offsets + (N + 1);                    // nTiles (<=256)
    int*    cursor  = rank;  // cursor path reuses rank slot (N <= E)

    size_t fixed = (size_t)N * BATCH * sizeof(float) + (size_t)E * sizeof(float4) +
                   ((size_t)2 * N + 1 + 256) * sizeof(int);
    size_t need_rank   = fixed + (size_t)E * sizeof(int);
    size_t need_cursor = fixed + (size_t)N * sizeof(int);

    if (ws_size >= need_rank && nTiles <= 256) {
        hipMemsetAsync(counts, 0, (size_t)N * sizeof(int), stream);
        k_transpose<<<(N + bt - 1) / bt, bt, 0, stream>>>(x, xT, N);
        k_hist_rank<<<gE4, bt, 0, stream>>>(dst, counts, rank, E);
        k_scan_tiles<<<nTiles, 256, 0, stream>>>(counts, offsets, tileSums, N);
        k_scan_sums<<<1, 256, 0, stream>>>(tileSums, offsets, nTiles, N, E);
        k_add<<<(N + bt - 1) / bt, bt, 0, stream>>>(offsets, tileSums, N);
        k_scatter_rank<<<gE4, bt, 0, stream>>>(src, dst, ea, ew, eb, rank, offsets, sorted, E);
        k_gather<<<((size_t)N * 4 + bt - 1) / bt, bt, 0, stream>>>(sorted, offsets, xT, na, nw, nb, out, N);
    } else if (ws_size >= need_cursor && nTiles <= 256) {
        hipMemsetAsync(counts, 0, (size_t)N * sizeof(int), stream);
        k_transpose<<<(N + bt - 1) / bt, bt, 0, stream>>>(x, xT, N);
        k_hist<<<gE4, bt, 0, stream>>>(dst, counts, E);
        k_scan_tiles<<<nTiles, 256, 0, stream>>>(counts, offsets, tileSums, N);
        k_scan_sums<<<1, 256, 0, stream>>>(tileSums, offsets, nTiles, N, E);
        k_add_cursor<<<(N + bt - 1) / bt, bt, 0, stream>>>(offsets, tileSums, cursor, N);
        k_scatter<<<(E + bt - 1) / bt, bt, 0, stream>>>(src, dst, ea, ew, eb, cursor, sorted, E);
        k_gather<<<((size_t)N * 4 + bt - 1) / bt, bt, 0, stream>>>(sorted, offsets, xT, na, nw, nb, out, N);
    } else {
        hipMemsetAsync(d_out, 0, (size_t)out_size * sizeof(float), stream);
        k_edge_direct<<<(E + bt - 1) / bt, bt, 0, stream>>>(src, dst, ea, ew, eb, x, out, N, E);
        k_node_inplace<<<(N + bt - 1) / bt, bt, 0, stream>>>(na, nw, nb, out, N);
    }
}